// Round 5
// baseline (49.098 us; speedup 1.0000x reference)
//
#include <hip/hip_runtime.h>
#include <math.h>

// ---------------- workspace layout (float offsets) ----------------
// P2   : 32 * 8 * 196 = 50176   (per (n, c-chunk) partial small masks)
// MASK : 32 * 3136    = 100352  (final premultiplied mask v*a+b, fp32)
#define P2_OFF     33280
#define MASK_OFF   83456

// Fused: per-block column-sum chunk of conv_w + channel dot at 14x14.
// grid (32 n, 8 cc) x 256 threads.
// wsum[c] = sum_o conv_w[o][c]; the 1x1-conv + channel-mean commute, and the
// 1/C factor + conv_b drop out of the min-max norm entirely.
__global__ void k_mask_small(const float* __restrict__ emb,
                             const float* __restrict__ conv_w,
                             float* __restrict__ ws) {
    __shared__ float wpart[256];
    __shared__ float wl[64];
    int n  = blockIdx.x;   // 0..31
    int cc = blockIdx.y;   // 0..7
    int t  = threadIdx.x;  // 0..255

    // column partial sums: thread (rg,col) sums 64 rows of column cc*64+col
    int col = t & 63, rg = t >> 6;
    float a = 0.f;
    const float* wp = conv_w + (rg * 64) * 512 + cc * 64 + col;
#pragma unroll 8
    for (int k = 0; k < 64; ++k) a += wp[k * 512];
    wpart[t] = a;
    __syncthreads();
    if (t < 64) wl[t] = wpart[t] + wpart[t + 64] + wpart[t + 128] + wpart[t + 192];
    __syncthreads();

    if (t < 196) {
        const float* base = emb + (size_t)(n * 512 + cc * 64) * 196 + t;
        float acc = 0.f;
#pragma unroll 8
        for (int c = 0; c < 64; ++c) acc += base[c * 196] * wl[c];
        ws[P2_OFF + (n * 8 + cc) * 196 + t] = acc;
    }
}

// Per-sample: combine partials -> 14x14 in LDS, bilinear upsample to 56x56
// (half-pixel, clamped == jax renormalized triangle kernel for scale 4),
// block min/max reduce, then store premultiplied mask m' = v*a + b with
// a = weight/(mx-mn), b = 1 - mn*a.  (The reference's second _minmax_norm is
// exactly identity after the first.)
__global__ void k_upsample(const float* __restrict__ wgt_p, float* __restrict__ ws) {
    __shared__ float sm[196];
    __shared__ float rmin[256], rmax[256];
    int n = blockIdx.x;   // 0..31
    int t = threadIdx.x;  // 0..255

    if (t < 196) {
        float a = 0.f;
#pragma unroll
        for (int k = 0; k < 8; ++k) a += ws[P2_OFF + (n * 8 + k) * 196 + t];
        sm[t] = a;
    }
    __syncthreads();

    float vmin = INFINITY, vmax = -INFINITY;
    for (int p = t; p < 3136; p += 256) {
        int h = p / 56, w = p % 56;
        float sy = (h + 0.5f) * 0.25f - 0.5f;
        float sx = (w + 0.5f) * 0.25f - 0.5f;
        int y0 = (int)floorf(sy); float fy = sy - (float)y0;
        int x0 = (int)floorf(sx); float fx = sx - (float)x0;
        int y1 = min(y0 + 1, 13); y0 = max(y0, 0);
        int x1 = min(x0 + 1, 13); x0 = max(x0, 0);
        float v00 = sm[y0 * 14 + x0], v01 = sm[y0 * 14 + x1];
        float v10 = sm[y1 * 14 + x0], v11 = sm[y1 * 14 + x1];
        float v = (1.f - fy) * ((1.f - fx) * v00 + fx * v01)
                +        fy  * ((1.f - fx) * v10 + fx * v11);
        vmin = fminf(vmin, v);
        vmax = fmaxf(vmax, v);
    }
    rmin[t] = vmin; rmax[t] = vmax;
    __syncthreads();
    for (int s = 128; s > 0; s >>= 1) {
        if (t < s) {
            rmin[t] = fminf(rmin[t], rmin[t + s]);
            rmax[t] = fmaxf(rmax[t], rmax[t + s]);
        }
        __syncthreads();
    }
    float mn = rmin[0], mx = rmax[0];
    float a = wgt_p[0] / (mx - mn);
    float b = 1.f - mn * a;

    for (int p = t; p < 3136; p += 256) {
        int h = p / 56, w = p % 56;
        float sy = (h + 0.5f) * 0.25f - 0.5f;
        float sx = (w + 0.5f) * 0.25f - 0.5f;
        int y0 = (int)floorf(sy); float fy = sy - (float)y0;
        int x0 = (int)floorf(sx); float fx = sx - (float)x0;
        int y1 = min(y0 + 1, 13); y0 = max(y0, 0);
        int x1 = min(x0 + 1, 13); x0 = max(x0, 0);
        float v00 = sm[y0 * 14 + x0], v01 = sm[y0 * 14 + x1];
        float v10 = sm[y1 * 14 + x0], v11 = sm[y1 * 14 + x1];
        float v = (1.f - fy) * ((1.f - fx) * v00 + fx * v01)
                +        fy  * ((1.f - fx) * v10 + fx * v11);
        ws[MASK_OFF + n * 3136 + p] = v * a + b;
    }
}

// Big elementwise pass: out = sigmoid(x) * m'.
// grid (98 seg, 32 n) x 256 threads; each block owns 2048 contiguous float4
// of one sample -> 8 independent iterations per thread (16 outstanding VMEM
// loads/wave trip) for latency hiding. One %784 at entry; per-iter mask
// phase via cheap mod-chain (no division in loop). Mask read from global:
// 400 KB/sample working set, L2-hot.
__global__ void __launch_bounds__(256) k_final(const float4* __restrict__ x4,
                                               const float* __restrict__ ws,
                                               float4* __restrict__ out4) {
    const int t = threadIdx.x;
    const int s = blockIdx.x;          // 0..97  segment
    const int n = blockIdx.y;          // 0..31  sample
    const float4* m4 = (const float4*)(ws + MASK_OFF) + n * 784;

    const long base = (long)n * 200704 + (long)s * 2048;
    const float4* xp = x4   + base;
    float4*       op = out4 + base;

    // phase of float4 (base + t) within the 784-float4 mask plane:
    // 2048 % 784 == 480
    int q = (s * 480 + t) % 784;

#pragma unroll
    for (int i = 0; i < 8; ++i) {
        float4 x = xp[i * 256 + t];
        float4 m = m4[q];
        float4 o;
        o.x = m.x * __builtin_amdgcn_rcpf(1.f + __expf(-x.x));
        o.y = m.y * __builtin_amdgcn_rcpf(1.f + __expf(-x.y));
        o.z = m.z * __builtin_amdgcn_rcpf(1.f + __expf(-x.z));
        o.w = m.w * __builtin_amdgcn_rcpf(1.f + __expf(-x.w));
        op[i * 256 + t] = o;
        q += 256;
        if (q >= 784) q -= 784;
    }
}

extern "C" void kernel_launch(void* const* d_in, const int* in_sizes, int n_in,
                              void* d_out, int out_size, void* d_ws, size_t ws_size,
                              hipStream_t stream) {
    const float* main_in = (const float*)d_in[0];  // [32,256,56,56]
    const float* emb_in  = (const float*)d_in[1];  // [32,512,14,14]
    const float* conv_w  = (const float*)d_in[2];  // [256,512]
    // d_in[3] = conv_b : provably dead (shift-invariant under min-max norm)
    const float* weight  = (const float*)d_in[4];  // scalar

    float* ws   = (float*)d_ws;
    float4* out = (float4*)d_out;

    k_mask_small<<<dim3(32, 8),  256, 0, stream>>>(emb_in, conv_w, ws);
    k_upsample  <<<32,           256, 0, stream>>>(weight, ws);
    k_final     <<<dim3(98, 32), 256, 0, stream>>>((const float4*)main_in, ws, out);
}

// Round 6
// 46.338 us; speedup vs baseline: 1.0596x; 1.0596x over previous
//
#include <hip/hip_runtime.h>
#include <math.h>

// ---------------- workspace layout (float offsets) ----------------
// P2 : 32 * 8 * 196 = 50176  (per (n, c-chunk) partial small masks)
#define P2_OFF 0

// Fused: per-block column-sum chunk of conv_w + channel dot at 14x14.
// grid (32 n, 8 cc) x 256 threads.
// wsum[c] = sum_o conv_w[o][c]; 1x1-conv + channel-mean commute; the 1/C
// factor and conv_b drop out of the min-max norm entirely.
__global__ void k_mask_small(const float* __restrict__ emb,
                             const float* __restrict__ conv_w,
                             float* __restrict__ ws) {
    __shared__ float wpart[256];
    __shared__ float wl[64];
    int n  = blockIdx.x;   // 0..31
    int cc = blockIdx.y;   // 0..7
    int t  = threadIdx.x;  // 0..255

    int col = t & 63, rg = t >> 6;
    float a = 0.f;
    const float* wp = conv_w + (rg * 64) * 512 + cc * 64 + col;
#pragma unroll 8
    for (int k = 0; k < 64; ++k) a += wp[k * 512];
    wpart[t] = a;
    __syncthreads();
    if (t < 64) wl[t] = wpart[t] + wpart[t + 64] + wpart[t + 128] + wpart[t + 192];
    __syncthreads();

    if (t < 196) {
        const float* base = emb + (size_t)(n * 512 + cc * 64) * 196 + t;
        float acc = 0.f;
#pragma unroll 8
        for (int c = 0; c < 64; ++c) acc += base[c * 196] * wl[c];
        ws[P2_OFF + (n * 8 + cc) * 196 + t] = acc;
    }
}

// Fused big pass: out = sigmoid(x) * (mask*weight + 1), mask in-register.
// grid (98 seg, 32 n) x 256 threads; each block owns 2048 contiguous float4
// of one sample. Prologue (hidden under the 8 prefetched HBM loads):
//  - rebuild 14x14 plane sm[196] from P2 partials (L2-hot),
//  - redundant min/max sweep over the 3136 upsampled values (identical
//    order in every block -> identical a,b; deterministic),
//  - a = weight/(mx-mn), b = 1 - mn*a.
// Main loop: decode mask float4 (row r = q/14, quad wq = q%14; fx pattern
// {.625,.875,.125,.375} with edge clamping == jax half-pixel linear resize),
// 6 LDS reads + lerps, then o = (v*a+b) * sigmoid(x).
__global__ void __launch_bounds__(256) k_final(const float4* __restrict__ x4,
                                               const float* __restrict__ ws,
                                               const float* __restrict__ wgt_p,
                                               float4* __restrict__ out4) {
    __shared__ float sm[196];
    __shared__ float wred[8];
    const int t = threadIdx.x;
    const int s = blockIdx.x;          // 0..97  segment
    const int n = blockIdx.y;          // 0..31  sample

    const long base = (long)n * 200704 + (long)s * 2048;
    const float4* xp = x4   + base;
    float4*       op = out4 + base;

    float wgt = wgt_p[0];

    // prefetch the 8 input float4s first; mask prologue hides their latency
    float4 x[8];
#pragma unroll
    for (int i = 0; i < 8; ++i) x[i] = xp[i * 256 + t];

    if (t < 196) {
        float a = 0.f;
#pragma unroll
        for (int k = 0; k < 8; ++k) a += ws[P2_OFF + (n * 8 + k) * 196 + t];
        sm[t] = a;
    }
    __syncthreads();

    // min/max over the upsampled 56x56 plane (reference bilinear form)
    float vmin = INFINITY, vmax = -INFINITY;
    for (int p = t; p < 3136; p += 256) {
        int h = p / 56, w = p % 56;
        float sy = (h + 0.5f) * 0.25f - 0.5f;
        float sx = (w + 0.5f) * 0.25f - 0.5f;
        int y0 = (int)floorf(sy); float fy = sy - (float)y0;
        int x0 = (int)floorf(sx); float fx = sx - (float)x0;
        int y1 = min(y0 + 1, 13); y0 = max(y0, 0);
        int x1 = min(x0 + 1, 13); x0 = max(x0, 0);
        float v00 = sm[y0 * 14 + x0], v01 = sm[y0 * 14 + x1];
        float v10 = sm[y1 * 14 + x0], v11 = sm[y1 * 14 + x1];
        float v = (1.f - fy) * ((1.f - fx) * v00 + fx * v01)
                +        fy  * ((1.f - fx) * v10 + fx * v11);
        vmin = fminf(vmin, v);
        vmax = fmaxf(vmax, v);
    }
    // wave reduce (64 lanes), then one LDS hop across the 4 waves
#pragma unroll
    for (int off = 32; off > 0; off >>= 1) {
        vmin = fminf(vmin, __shfl_xor(vmin, off, 64));
        vmax = fmaxf(vmax, __shfl_xor(vmax, off, 64));
    }
    if ((t & 63) == 0) { wred[t >> 6] = vmin; wred[4 + (t >> 6)] = vmax; }
    __syncthreads();
    float mn = fminf(fminf(wred[0], wred[1]), fminf(wred[2], wred[3]));
    float mx = fmaxf(fmaxf(wred[4], wred[5]), fmaxf(wred[6], wred[7]));
    float a = wgt / (mx - mn);
    float b = 1.f - mn * a;

    // mask float4-phase of (base + t) in the 784-float4 plane: 2048%784==480
    const int q0 = (s * 480 + t) % 784;

#pragma unroll
    for (int i = 0; i < 8; ++i) {
        // c_i = (i*256) % 784 precomputed; q0 + c_i < 1568 -> one subtract
        const int ci = (i * 256) % 784;
        int q = q0 + ci;
        if (q >= 784) q -= 784;
        int r  = (q * 4682) >> 16;     // q / 14  (valid for q < 784)
        int wq = q - r * 14;
        float sy = r * 0.25f - 0.375f;
        int y0 = (int)floorf(sy);
        float fy = sy - (float)y0;
        int y1 = min(y0 + 1, 13); y0 = max(y0, 0);
        int xm  = max(wq - 1, 0);
        int xp1 = min(wq + 1, 13);
        float t0 = sm[y0 * 14 + xm], t1 = sm[y0 * 14 + wq], t2 = sm[y0 * 14 + xp1];
        float b0 = sm[y1 * 14 + xm], b1 = sm[y1 * 14 + wq], b2 = sm[y1 * 14 + xp1];
        // column phases for the 4 pixels of this float4:
        // j=0: x0=wq-1, fx=.625  j=1: x0=wq-1, fx=.875
        // j=2: x0=wq,   fx=.125  j=3: x0=wq,   fx=.375
        float m0t = t0 + 0.625f * (t1 - t0), m0b = b0 + 0.625f * (b1 - b0);
        float m1t = t0 + 0.875f * (t1 - t0), m1b = b0 + 0.875f * (b1 - b0);
        float m2t = t1 + 0.125f * (t2 - t1), m2b = b1 + 0.125f * (b2 - b1);
        float m3t = t1 + 0.375f * (t2 - t1), m3b = b1 + 0.375f * (b2 - b1);
        float m0 = m0t + fy * (m0b - m0t);
        float m1 = m1t + fy * (m1b - m1t);
        float m2 = m2t + fy * (m2b - m2t);
        float m3 = m3t + fy * (m3b - m3t);

        float4 xi = x[i];
        float4 o;
        o.x = (m0 * a + b) * __builtin_amdgcn_rcpf(1.f + __expf(-xi.x));
        o.y = (m1 * a + b) * __builtin_amdgcn_rcpf(1.f + __expf(-xi.y));
        o.z = (m2 * a + b) * __builtin_amdgcn_rcpf(1.f + __expf(-xi.z));
        o.w = (m3 * a + b) * __builtin_amdgcn_rcpf(1.f + __expf(-xi.w));
        op[i * 256 + t] = o;
    }
}

extern "C" void kernel_launch(void* const* d_in, const int* in_sizes, int n_in,
                              void* d_out, int out_size, void* d_ws, size_t ws_size,
                              hipStream_t stream) {
    const float* main_in = (const float*)d_in[0];  // [32,256,56,56]
    const float* emb_in  = (const float*)d_in[1];  // [32,512,14,14]
    const float* conv_w  = (const float*)d_in[2];  // [256,512]
    // d_in[3] = conv_b : provably dead (shift-invariant under min-max norm)
    const float* weight  = (const float*)d_in[4];  // scalar

    float* ws   = (float*)d_ws;
    float4* out = (float4*)d_out;

    k_mask_small<<<dim3(32, 8),  256, 0, stream>>>(emb_in, conv_w, ws);
    k_final     <<<dim3(98, 32), 256, 0, stream>>>((const float4*)main_in, ws, weight, out);
}